// Round 1
// baseline (4608.119 us; speedup 1.0000x reference)
//
#include <hip/hip_runtime.h>
#include <cstdint>
#include <cstddef>

typedef unsigned short u16;
typedef __attribute__((ext_vector_type(8))) short short8;
typedef __attribute__((ext_vector_type(4))) float f32x4;

#define SEQ 128
#define BATCH 256
#define HID 1024
#define LSZ 262144  // BATCH*HID
#define NROWS 32768 // SEQ*BATCH

#define MFMA(a,b,c) __builtin_amdgcn_mfma_f32_16x16x32_bf16((a),(b),(c),0,0,0)

__device__ __forceinline__ u16 f2b(float f) {
  union { float f; unsigned u; } v; v.f = f;
  unsigned r = (v.u + 0x7FFFu + ((v.u >> 16) & 1u)) >> 16;
  return (u16)r;
}
__device__ __forceinline__ float b2f(u16 h) {
  union { unsigned u; float f; } v; v.u = ((unsigned)h) << 16; return v.f;
}
__device__ __forceinline__ float sigm(float x){ return 1.f/(1.f + __expf(-x)); }
__device__ __forceinline__ float tanh_f(float x){
  x = fminf(15.f, fmaxf(-15.f, x));
  float e = __expf(2.f*x); return (e-1.f)/(e+1.f);
}
__device__ __forceinline__ float eluf(float x){ return x > 0.f ? x : expm1f(x); }

// ---------------- workspace layout (bytes) ----------------
static const size_t OFF_W0T  = 0;                       // 4096*1088*2
static const size_t OFF_W1T  = 8912896;                 // 4096*2048*2
static const size_t OFF_XBF  = 25690112;                // 32768*64*2
static const size_t OFF_H0U  = 29884416;                // 2*LSZ*2
static const size_t OFF_H0M  = 30932992;                // 2*LSZ*2
static const size_t OFF_H1M  = 31981568;                // 2*LSZ*2
static const size_t OFF_C0   = 33030144;                // LSZ*4
static const size_t OFF_C1   = 34078720;                // LSZ*4
static const size_t OFF_HS   = 35127296;                // 32768*1024*2
static const size_t OFF_BS0  = 102236160;               // 4096*4
static const size_t OFF_BS1  = 102252544;
static const size_t OFF_MU   = 102268928;               // 32768*4
static const size_t OFF_RSTD = 102400000;
static const size_t OFF_W1LN = 102531072;               // 512*1024*2
static const size_t OFF_S1   = 103579648;               // 512*4
static const size_t OFF_B1P  = 103581696;
static const size_t OFF_W2B  = 103583744;               // 128*512*2
static const size_t OFF_W3B  = 103714816;               // 64*128*2
static const size_t OFF_A1   = 103731200;               // 32768*512*2
static const size_t OFF_A2   = 137285632;               // 32768*128*2
static const size_t OFF_A3   = 145674240;               // 32768*64*2

// ---------------- prep kernels ----------------
// W0t: [colglob][k], colglob = hb*64 + g*16 + hl (gate-complete 16-h blocks), K=1088 = [x(64)|h(1024)]
__global__ void prep_w0t(const float* __restrict__ wih, const float* __restrict__ whh,
                         u16* __restrict__ out) {
  int cg = blockIdx.x;
  int hb = cg >> 6, c = cg & 63;
  int gg = c >> 4, hl = c & 15;
  int gr = gg * HID + hb * 16 + hl;
  for (int k = threadIdx.x; k < 1088; k += 256) {
    float w = (k < 64) ? wih[gr * 64 + k] : whh[(size_t)gr * HID + (k - 64)];
    out[(size_t)cg * 1088 + k] = f2b(w);
  }
}
// W1t: K=2048 = [h0(1024)|h1(1024)]
__global__ void prep_w1t(const float* __restrict__ wih, const float* __restrict__ whh,
                         u16* __restrict__ out) {
  int cg = blockIdx.x;
  int hb = cg >> 6, c = cg & 63;
  int gg = c >> 4, hl = c & 15;
  int gr = gg * HID + hb * 16 + hl;
  for (int k = threadIdx.x; k < 2048; k += 256) {
    float w = (k < 1024) ? wih[(size_t)gr * HID + k] : whh[(size_t)gr * HID + (k - 1024)];
    out[(size_t)cg * 2048 + k] = f2b(w);
  }
}
// W1ln = bf16(W1*ln_g), S1[j] = sum_k bf16(W1*g), b1p[j] = b1[j] + sum_k W1*ln_b
__global__ void prep_w1ln(const float* __restrict__ w1, const float* __restrict__ lng,
                          const float* __restrict__ lnb, const float* __restrict__ b1,
                          u16* __restrict__ w1ln, float* __restrict__ S1, float* __restrict__ b1p) {
  int j = blockIdx.x;
  float s = 0.f, bb = 0.f;
  for (int k = threadIdx.x; k < HID; k += 256) {
    float w = w1[(size_t)j * HID + k];
    u16 q = f2b(w * lng[k]);
    w1ln[(size_t)j * HID + k] = q;
    s += b2f(q);
    bb += w * lnb[k];
  }
  __shared__ float r1[256], r2[256];
  r1[threadIdx.x] = s; r2[threadIdx.x] = bb;
  __syncthreads();
  for (int o = 128; o > 0; o >>= 1) {
    if (threadIdx.x < (unsigned)o) { r1[threadIdx.x] += r1[threadIdx.x+o]; r2[threadIdx.x] += r2[threadIdx.x+o]; }
    __syncthreads();
  }
  if (threadIdx.x == 0) { S1[j] = r1[0]; b1p[j] = b1[j] + r2[0]; }
}
// misc inits: biases, x->bf16, masked initial h, c copies, mlp weight casts
__global__ void prep_misc(const float* bih0, const float* bhh0, const float* bih1, const float* bhh1,
                          const float* x, const float* h0in, const float* c0in,
                          const float* w2, const float* w3, const int* done,
                          float* bs0, float* bs1, u16* xbf, u16* h0m, u16* h1m,
                          float* c0buf, float* c1buf, u16* w2b, u16* w3b) {
  size_t i = (size_t)blockIdx.x * blockDim.x + threadIdx.x;
  if (i < 4096) { bs0[i] = bih0[i] + bhh0[i]; return; }
  i -= 4096;
  if (i < 4096) { bs1[i] = bih1[i] + bhh1[i]; return; }
  i -= 4096;
  if (i < 2097152) { xbf[i] = f2b(x[i]); return; }
  i -= 2097152;
  if (i < LSZ) { int row = (int)(i >> 10); h0m[i] = done[row] ? (u16)0 : f2b(h0in[i]); return; }          // h0m slot 0
  i -= LSZ;
  if (i < LSZ) { int row = (int)(i >> 10); h1m[LSZ + i] = done[row] ? (u16)0 : f2b(h0in[LSZ + i]); return; } // h1m slot 1
  i -= LSZ;
  if (i < LSZ) { c0buf[i] = c0in[i]; return; }
  i -= LSZ;
  if (i < LSZ) { c1buf[i] = c0in[LSZ + i]; return; }
  i -= LSZ;
  if (i < 65536) { w2b[i] = f2b(w2[i]); return; }
  i -= 65536;
  if (i < 8192) { w3b[i] = f2b(w3[i]); return; }
}

// ---------------- recurrence: stage s does layer0[t=s] and layer1[t=s-1] ----------------
// block mapping: b&7 = XCD; hb = (b&7)*8 + (r&7) keeps each weight slice on one XCD's L2
__global__ __launch_bounds__(512, 4) void step_kernel(
    int s,
    const u16* __restrict__ w0t, const u16* __restrict__ w1t,
    const u16* __restrict__ xbf,
    u16* __restrict__ h0u, u16* __restrict__ h0m, u16* __restrict__ h1m,
    u16* __restrict__ hs,
    float* __restrict__ c0buf, float* __restrict__ c1buf,
    const float* __restrict__ bsum0, const float* __restrict__ bsum1,
    const int* __restrict__ done,
    float* __restrict__ dout)
{
  const int b = blockIdx.x;
  const int r = b >> 3;
  const int hb = (b & 7) * 8 + (r & 7);     // 0..63
  const int layer = (r >> 3) & 1;
  const int mt = r >> 4;                     // 0..3
  if (layer ? (s == 0) : (s == SEQ)) return;
  const int t = layer ? (s - 1) : s;

  const int tid = threadIdx.x;
  const int lane = tid & 63;
  const int wv = tid >> 6;
  const int g = wv & 3, rh = wv >> 2;
  const int quad = lane >> 4, c16 = lane & 15;
  const int rowbase = mt * 64;

  __shared__ u16 Al[8192];   // A stage, fragment-linear: [ks][rt][lane]*8
  __shared__ u16 Bl[8192];   // B stage, fragment-linear: [ks][gate][lane]*8
  __shared__ float gl[4][64][16];

  const int K   = layer ? 2048 : 1088;
  const int KC  = layer ? 128 : 64;
  const int NC  = layer ? 16 : 17;
  const int nslot = layer ? 2 : 1;

  const u16* Wt = layer ? w1t : w0t;
  const u16* aseg0; const u16* aseg1;
  int rs0, seg0len;
  if (layer) {
    aseg0 = h0u + (size_t)(t & 1) * LSZ; rs0 = HID; seg0len = 1024;   // h0 current (unmasked)
    aseg1 = h1m + (size_t)((t + 1) & 1) * LSZ;                        // h1[t-1]*mask
  } else {
    aseg0 = xbf + (size_t)t * BATCH * 64; rs0 = 64; seg0len = 64;     // x_t
    aseg1 = h0m + (size_t)(t & 1) * LSZ;                              // h0[t-1]*mask
  }

  // staging decode (slot = tid + i*512): sub = ks*4 + idx4, content row/col = idx4*16+(lp&15), kl = ks*32+(lp>>4)*8
  int arow[2], akl[2];
  const u16* bgp[2];
  #pragma unroll
  for (int i = 0; i < 2; ++i) {
    int sA = tid + i * 512;
    int sub = sA >> 6, lp = sA & 63;
    int ks = sub >> 2, i4 = sub & 3;
    arow[i] = i4 * 16 + (lp & 15);
    akl[i]  = ks * 32 + (lp >> 4) * 8;
    bgp[i] = Wt + (size_t)(hb * 64 + i4 * 16 + (lp & 15)) * K + akl[i];
  }

  short8 vA[2], vB[2];
  f32x4 acc0 = {0.f,0.f,0.f,0.f}, acc1 = {0.f,0.f,0.f,0.f};

  auto load_stage = [&](int ci) {
    int kc = ci * KC;
    #pragma unroll
    for (int i = 0; i < 2; ++i) {
      if (i < nslot) {
        const u16* p;
        if (kc < seg0len) p = aseg0 + (size_t)(rowbase + arow[i]) * rs0 + kc + akl[i];
        else              p = aseg1 + (size_t)(rowbase + arow[i]) * HID + (kc - seg0len) + akl[i];
        vA[i] = *(const short8*)p;
        vB[i] = *(const short8*)(bgp[i] + kc);
      }
    }
  };

  load_stage(0);
  const int rt0 = rh * 2, rt1 = rt0 + 1;
  for (int ci = 0; ci < NC; ++ci) {
    // commit regs -> LDS
    *(short8*)&Al[(size_t)tid * 8] = vA[0];
    *(short8*)&Bl[(size_t)tid * 8] = vB[0];
    if (nslot == 2) {
      *(short8*)&Al[(size_t)(tid + 512) * 8] = vA[1];
      *(short8*)&Bl[(size_t)(tid + 512) * 8] = vB[1];
    }
    __syncthreads();
    if (ci + 1 < NC) load_stage(ci + 1);   // overlap with compute
    #define KSTEP(ks) { \
      short8 af0 = *(const short8*)&Al[(((ks)*4 + rt0)*64 + lane) * 8]; \
      short8 af1 = *(const short8*)&Al[(((ks)*4 + rt1)*64 + lane) * 8]; \
      short8 bf  = *(const short8*)&Bl[(((ks)*4 + g  )*64 + lane) * 8]; \
      acc0 = MFMA(af0, bf, acc0); acc1 = MFMA(af1, bf, acc1); }
    if (layer) { KSTEP(0) KSTEP(1) KSTEP(2) KSTEP(3) }
    else       { KSTEP(0) KSTEP(1) }
    #undef KSTEP
    __syncthreads();
  }

  // ---- epilogue: cross-gate exchange + LSTM cell ----
  #pragma unroll
  for (int rg = 0; rg < 4; ++rg) {
    gl[g][rt0*16 + quad*4 + rg][c16] = acc0[rg];
    gl[g][rt1*16 + quad*4 + rg][c16] = acc1[rg];
  }
  __syncthreads();
  const float* bs = layer ? bsum1 : bsum0;
  float* cb = layer ? c1buf : c0buf;
  #pragma unroll
  for (int cc = 0; cc < 2; ++cc) {
    int cell = tid + cc * 512;
    int lr = cell >> 4, hl = cell & 15;
    int row = rowbase + lr;
    int h = hb * 16 + hl;
    float iv = gl[0][lr][hl] + bs[h];
    float fv = gl[1][lr][hl] + bs[HID + h];
    float gv = gl[2][lr][hl] + bs[2*HID + h];
    float ov = gl[3][lr][hl] + bs[3*HID + h];
    float m = done[t * BATCH + row] ? 0.f : 1.f;
    float cp = cb[(size_t)row * HID + h] * m;
    float c2 = sigm(fv) * cp + sigm(iv) * tanh_f(gv);
    float h2 = sigm(ov) * tanh_f(c2);
    cb[(size_t)row * HID + h] = c2;
    u16 hbv = f2b(h2);
    size_t idx = (size_t)row * HID + h;
    if (layer) {
      hs[(size_t)t * LSZ + idx] = hbv;
      if (t < SEQ-1) h1m[(size_t)(t & 1) * LSZ + idx] = done[(t+1)*BATCH + row] ? (u16)0 : hbv;
      else { dout[32768 + LSZ + idx] = h2; dout[32768 + 3*LSZ + idx] = c2; }
    } else {
      h0u[(size_t)(t & 1) * LSZ + idx] = hbv;
      if (t < SEQ-1) h0m[(size_t)((t+1) & 1) * LSZ + idx] = done[(t+1)*BATCH + row] ? (u16)0 : hbv;
      else { dout[32768 + idx] = h2; dout[32768 + 2*LSZ + idx] = c2; }
    }
  }
}

// ---------------- LayerNorm row stats over hs ----------------
__global__ void ln_stats(const u16* __restrict__ hs, float* __restrict__ mu, float* __restrict__ rstd) {
  int row = blockIdx.x * 4 + (threadIdx.x >> 6);
  int lane = threadIdx.x & 63;
  const short8* p = (const short8*)(hs + (size_t)row * HID + lane * 16);
  short8 v0 = p[0], v1 = p[1];
  float s = 0.f, q = 0.f;
  #pragma unroll
  for (int e = 0; e < 8; ++e) {
    float a = b2f((u16)v0[e]); s += a; q += a*a;
    float b = b2f((u16)v1[e]); s += b; q += b*b;
  }
  for (int o = 32; o > 0; o >>= 1) { s += __shfl_xor(s, o); q += __shfl_xor(q, o); }
  if (lane == 0) {
    float m = s * (1.f/1024.f);
    float var = q * (1.f/1024.f) - m*m;
    mu[row] = m; rstd[row] = rsqrtf(var + 1e-5f);
  }
}

// ---------------- generic MLP GEMM: 128x128 tile, fused LN/bias + ELU epilogue ----------------
__global__ __launch_bounds__(512, 4) void mlp_gemm(
    const u16* __restrict__ A, int lda, const u16* __restrict__ B, int K, int N,
    u16* __restrict__ out, int ldo, int mode,
    const float* __restrict__ mu, const float* __restrict__ rstd,
    const float* __restrict__ S1v, const float* __restrict__ bias)
{
  const int nt = blockIdx.x, mtb = blockIdx.y;
  const int tid = threadIdx.x, lane = tid & 63, wv = tid >> 6;
  const int quad = lane >> 4, c16 = lane & 15;
  __shared__ u16 Am[16384], Bm[16384];
  f32x4 acc[8];
  #pragma unroll
  for (int i = 0; i < 8; ++i) acc[i] = (f32x4){0.f,0.f,0.f,0.f};

  int arow[4], akl[4], bcol[4];
  #pragma unroll
  for (int i = 0; i < 4; ++i) {
    int s = tid + i * 512, sub = s >> 6, lp = s & 63;
    int ks = sub >> 3, u = sub & 7;
    arow[i] = mtb * 128 + u * 16 + (lp & 15);
    akl[i]  = ks * 32 + (lp >> 4) * 8;
    bcol[i] = nt * 128 + u * 16 + (lp & 15);
  }
  short8 vA[4], vB[4];
  const short8 z8 = {0,0,0,0,0,0,0,0};
  const int NCH = K >> 7;
  auto load_stage = [&](int ci) {
    int kc = ci << 7;
    #pragma unroll
    for (int i = 0; i < 4; ++i) {
      vA[i] = *(const short8*)(A + (size_t)arow[i] * lda + kc + akl[i]);
      vB[i] = (bcol[i] < N) ? *(const short8*)(B + (size_t)bcol[i] * K + kc + akl[i]) : z8;
    }
  };
  load_stage(0);
  for (int ci = 0; ci < NCH; ++ci) {
    #pragma unroll
    for (int i = 0; i < 4; ++i) {
      *(short8*)&Am[(size_t)(tid + i*512) * 8] = vA[i];
      *(short8*)&Bm[(size_t)(tid + i*512) * 8] = vB[i];
    }
    __syncthreads();
    if (ci + 1 < NCH) load_stage(ci + 1);
    #pragma unroll
    for (int ks = 0; ks < 4; ++ks) {
      short8 bf = *(const short8*)&Bm[((ks*8 + wv)*64 + lane) * 8];
      #pragma unroll
      for (int rt = 0; rt < 8; ++rt) {
        short8 af = *(const short8*)&Am[((ks*8 + rt)*64 + lane) * 8];
        acc[rt] = MFMA(af, bf, acc[rt]);
      }
    }
    __syncthreads();
  }
  int col = nt * 128 + wv * 16 + c16;
  if (col < N) {
    #pragma unroll
    for (int rt = 0; rt < 8; ++rt) {
      #pragma unroll
      for (int rg = 0; rg < 4; ++rg) {
        int row = mtb * 128 + rt * 16 + quad * 4 + rg;
        float v = acc[rt][rg];
        if (mode == 0) v = v * rstd[row] - mu[row] * rstd[row] * S1v[col] + bias[col];
        else           v = v + bias[col];
        v = eluf(v);
        out[(size_t)row * ldo + col] = f2b(v);
      }
    }
  }
}

// ---------------- value head: (32768,64) @ (64,1) + bv ----------------
__global__ void value_head(const u16* __restrict__ a3, const float* __restrict__ wv,
                           const float* __restrict__ bv, float* __restrict__ dout) {
  int row = blockIdx.x * 256 + threadIdx.x;
  const short8* p = (const short8*)(a3 + (size_t)row * 64);
  float s = bv[0];
  #pragma unroll
  for (int j = 0; j < 8; ++j) {
    short8 v = p[j];
    #pragma unroll
    for (int e = 0; e < 8; ++e) s += b2f((u16)v[e]) * wv[j*8+e];
  }
  dout[row] = s;
}

extern "C" void kernel_launch(void* const* d_in, const int* in_sizes, int n_in,
                              void* d_out, int out_size, void* d_ws, size_t ws_size,
                              hipStream_t stream) {
  (void)in_sizes; (void)n_in; (void)out_size; (void)ws_size;
  const float* x    = (const float*)d_in[0];
  const int*   done = (const int*)d_in[1];
  const float* h0in = (const float*)d_in[2];
  const float* c0in = (const float*)d_in[3];
  const float* wih0 = (const float*)d_in[4];
  const float* whh0 = (const float*)d_in[5];
  const float* bih0 = (const float*)d_in[6];
  const float* bhh0 = (const float*)d_in[7];
  const float* wih1 = (const float*)d_in[8];
  const float* whh1 = (const float*)d_in[9];
  const float* bih1 = (const float*)d_in[10];
  const float* bhh1 = (const float*)d_in[11];
  const float* lng  = (const float*)d_in[12];
  const float* lnb  = (const float*)d_in[13];
  const float* w1   = (const float*)d_in[14];
  const float* b1   = (const float*)d_in[15];
  const float* w2   = (const float*)d_in[16];
  const float* b2   = (const float*)d_in[17];
  const float* w3   = (const float*)d_in[18];
  const float* b3   = (const float*)d_in[19];
  const float* wvp  = (const float*)d_in[20];
  const float* bvp  = (const float*)d_in[21];
  float* dout = (float*)d_out;
  char* ws = (char*)d_ws;

  u16*   w0t  = (u16*)(ws + OFF_W0T);
  u16*   w1t  = (u16*)(ws + OFF_W1T);
  u16*   xbf  = (u16*)(ws + OFF_XBF);
  u16*   h0u  = (u16*)(ws + OFF_H0U);
  u16*   h0m  = (u16*)(ws + OFF_H0M);
  u16*   h1m  = (u16*)(ws + OFF_H1M);
  float* c0b  = (float*)(ws + OFF_C0);
  float* c1b  = (float*)(ws + OFF_C1);
  u16*   hsb  = (u16*)(ws + OFF_HS);
  float* bs0  = (float*)(ws + OFF_BS0);
  float* bs1  = (float*)(ws + OFF_BS1);
  float* mu   = (float*)(ws + OFF_MU);
  float* rstd = (float*)(ws + OFF_RSTD);
  u16*   w1ln = (u16*)(ws + OFF_W1LN);
  float* s1   = (float*)(ws + OFF_S1);
  float* b1p  = (float*)(ws + OFF_B1P);
  u16*   w2b  = (u16*)(ws + OFF_W2B);
  u16*   w3b  = (u16*)(ws + OFF_W3B);
  u16*   a1   = (u16*)(ws + OFF_A1);
  u16*   a2   = (u16*)(ws + OFF_A2);
  u16*   a3   = (u16*)(ws + OFF_A3);

  prep_w0t<<<4096, 256, 0, stream>>>(wih0, whh0, w0t);
  prep_w1t<<<4096, 256, 0, stream>>>(wih1, whh1, w1t);
  prep_w1ln<<<512, 256, 0, stream>>>(w1, lng, lnb, b1, w1ln, s1, b1p);
  prep_misc<<<12608, 256, 0, stream>>>(bih0, bhh0, bih1, bhh1, x, h0in, c0in, w2, w3, done,
                                       bs0, bs1, xbf, h0m, h1m, c0b, c1b, w2b, w3b);

  for (int s = 0; s <= SEQ; ++s)
    step_kernel<<<512, 512, 0, stream>>>(s, w0t, w1t, xbf, h0u, h0m, h1m, hsb,
                                         c0b, c1b, bs0, bs1, done, dout);

  ln_stats<<<8192, 256, 0, stream>>>(hsb, mu, rstd);
  mlp_gemm<<<dim3(4, 256), 512, 0, stream>>>(hsb, 1024, w1ln, 1024, 512, a1, 512, 0, mu, rstd, s1, b1p);
  mlp_gemm<<<dim3(1, 256), 512, 0, stream>>>(a1, 512, w2b, 512, 128, a2, 128, 1, mu, rstd, s1, b2);
  mlp_gemm<<<dim3(1, 256), 512, 0, stream>>>(a2, 128, w3b, 128, 64, a3, 64, 1, mu, rstd, s1, b3);
  value_head<<<128, 256, 0, stream>>>(a3, wvp, bvp, dout);
}